// Round 13
// baseline (97.253 us; speedup 1.0000x reference)
//
#include <hip/hip_runtime.h>
#include <stdint.h>

#define B_DET 8192
#define N_DIM 256
#define T_TRK 4096
#define Q_SLOT 64
#define MAXD   64          // list capacity; P(D>64) ~ 0 for Binomial(8192, 1/4096)
#define EPSF   1e-9f

typedef unsigned long long ull;
typedef float nfloat4 __attribute__((ext_vector_type(4)));   // native vec for nt builtins

// Monotone map fp32 -> uint32 (ascending), and its exact inverse.
__device__ __forceinline__ uint32_t f32_key(float f) {
    uint32_t u = __float_as_uint(f);
    return (u & 0x80000000u) ? ~u : (u | 0x80000000u);
}
__device__ __forceinline__ float key_inv(uint32_t k) {
    uint32_t u = (k & 0x80000000u) ? (k ^ 0x80000000u) : ~k;
    return __uint_as_float(u);
}

__device__ __forceinline__ void nt_store_f4(float* p, float4 v) {
    nfloat4 nv; nv.x = v.x; nv.y = v.y; nv.z = v.z; nv.w = v.w;
    __builtin_nontemporal_store(nv, reinterpret_cast<nfloat4*>(p));
}

// Prep (merged): 2048 blocks x 256. Each block: 4 detection-row norms (one
// per wave, full-wave butterfly) + buckets 4 detections (threads 0..3).
// cnt[] must be zeroed beforehand. List order is nondeterministic (atomics)
// but argmin compares by VALUE (key, b, d) -> selection order-independent.
__global__ __launch_bounds__(256)
void prep(const float* __restrict__ reprs, const int* __restrict__ track_idxs,
          int* __restrict__ cnt, int* __restrict__ list,
          float* __restrict__ norm2) {
    const int wave = threadIdx.x >> 6;
    const int lane = threadIdx.x & 63;
    const int row  = blockIdx.x * 4 + wave;

    const float4 v = reinterpret_cast<const float4*>(reprs + (size_t)row * N_DIM)[lane];
    float ss = v.x * v.x + v.y * v.y + v.z * v.z + v.w * v.w;
    #pragma unroll
    for (int o = 32; o >= 1; o >>= 1) ss += __shfl_xor(ss, o, 64);
    if (lane == 0) norm2[row] = ss;

    if (threadIdx.x < 4) {
        const int b = blockIdx.x * 4 + threadIdx.x;
        const int t = track_idxs[b];
        const int slot = atomicAdd(&cnt[t], 1);
        if (slot < MAXD) list[t * MAXD + slot] = b;
    }
}

// Pass 2: block = one track (4096 blocks, XCD-contiguous swizzle); wave =
// quarter-track (16 rows) as 4 units of 4 rows. Grouped layout: lane l
// (group g=l>>4, col c=l&15) holds float4-columns c, c+16, c+32, c+48 of
// memory row qb + u*4 + g. All 16 rows preloaded (16 KB/wave in flight);
// d-loop reduces 4 units at once -> 4-wide butterfly ILP (xor 8,4,2,1).
// Detection rows read from global (L1/L2-hot), pipelined one ahead.
// Argmin: packed (f32key(dot), b, d) u64 min == exact first-occurrence
// tie-break. Norm closed-form (memory rows unit-norm):
//   ||a*m+(1-a)r||^2 = a^2 + (1-a)^2||r||^2 + 2a(1-a)dot,
// dot decoded bit-exactly from the winning key, ||r||^2 looked up.
// All out-stores NONTEMPORAL (measured -14% in R10).
__global__ __launch_bounds__(256)
void fused_update(const float* __restrict__ reprs,
                  const float* __restrict__ memory,
                  const float* __restrict__ alpha,
                  const int* __restrict__ cnt,
                  const int* __restrict__ list,
                  const float* __restrict__ norm2,
                  float* __restrict__ out) {
    const int bid  = blockIdx.x;
    const int t    = (bid & 7) * (T_TRK >> 3) + (bid >> 3);   // 4096 % 8 == 0
    const int wave = threadIdx.x >> 6;
    const int lane = threadIdx.x & 63;
    const int g    = lane >> 4;
    const int cidx = lane & 15;
    const int qb   = wave * 16;
    const size_t tbase = (size_t)t * Q_SLOT * N_DIM;

    int D = cnt[t];
    if (D == 0) {
        // untouched track: 16 rows/wave register copy (16 loads in flight)
        const size_t rbase = tbase + (size_t)qb * N_DIM;
        float4 mm[16];
        #pragma unroll
        for (int s = 0; s < 16; ++s)
            mm[s] = reinterpret_cast<const float4*>(memory + rbase + (size_t)s * N_DIM)[lane];
        #pragma unroll
        for (int s = 0; s < 16; ++s)
            nt_store_f4(out + rbase + (size_t)s * N_DIM + lane * 4, mm[s]);
        return;
    }
    if (D > MAXD) D = MAXD;

    // grouped-layout preload of this wave's 16 memory rows
    float4 m[4][4];
    #pragma unroll
    for (int u = 0; u < 4; ++u) {
        const float* rp = memory + tbase + (size_t)(qb + u * 4 + g) * N_DIM;
        #pragma unroll
        for (int c = 0; c < 4; ++c)
            m[u][c] = reinterpret_cast<const float4*>(rp)[cidx + c * 16];
    }

    ull best[4] = { ~0ULL, ~0ULL, ~0ULL, ~0ULL };

    // software-pipelined detection loop (load d+1 while reducing d)
    int b_cur = list[t * MAXD];
    float4 rc[4];
    {
        const float* rp = reprs + (size_t)b_cur * N_DIM;
        #pragma unroll
        for (int cc = 0; cc < 4; ++cc)
            rc[cc] = reinterpret_cast<const float4*>(rp)[cidx + cc * 16];
    }

    for (int d = 0; d < D; ++d) {
        int b_nxt = 0;
        float4 rn[4];
        if (d + 1 < D) {
            b_nxt = list[t * MAXD + d + 1];
            const float* rp = reprs + (size_t)b_nxt * N_DIM;
            #pragma unroll
            for (int cc = 0; cc < 4; ++cc)
                rn[cc] = reinterpret_cast<const float4*>(rp)[cidx + cc * 16];
        }

        float p[4] = { 0.0f, 0.0f, 0.0f, 0.0f };
        #pragma unroll
        for (int cc = 0; cc < 4; ++cc) {
            #pragma unroll
            for (int u = 0; u < 4; ++u)
                p[u] += m[u][cc].x * rc[cc].x + m[u][cc].y * rc[cc].y
                      + m[u][cc].z * rc[cc].z + m[u][cc].w * rc[cc].w;
        }
        // 4-stage butterfly within each 16-lane group (4-wide ILP)
        #pragma unroll
        for (int o = 8; o >= 1; o >>= 1) {
            #pragma unroll
            for (int u = 0; u < 4; ++u)
                p[u] += __shfl_xor(p[u], o, 64);
        }

        const uint32_t bd = ((uint32_t)b_cur << 6) | (uint32_t)d;
        #pragma unroll
        for (int u = 0; u < 4; ++u) {
            const ull k = ((ull)f32_key(p[u]) << 32) | bd;
            if (k < best[u]) best[u] = k;
        }

        b_cur = b_nxt;
        #pragma unroll
        for (int cc = 0; cc < 4; ++cc) rc[cc] = rn[cc];
    }

    #pragma unroll
    for (int u = 0; u < 4; ++u) {
        const int q = qb + u * 4 + g;
        const int   bsel = (int)(((uint32_t)best[u]) >> 6);
        const float dot  = key_inv((uint32_t)(best[u] >> 32));
        const float a    = alpha[q];
        const float na   = 1.0f - a;

        const float* rp = reprs + (size_t)bsel * N_DIM;   // L1/L2-hot refetch
        const float nrm2 = a * a + na * na * norm2[bsel] + 2.0f * a * na * dot;
        const float sc = 1.0f / (sqrtf(nrm2) + EPSF);

        float* op = out + tbase + (size_t)q * N_DIM;
        #pragma unroll
        for (int cc = 0; cc < 4; ++cc) {
            const float4 r = reinterpret_cast<const float4*>(rp)[cidx + cc * 16];
            float4 w;
            w.x = (a * m[u][cc].x + na * r.x) * sc;
            w.y = (a * m[u][cc].y + na * r.y) * sc;
            w.z = (a * m[u][cc].z + na * r.z) * sc;
            w.w = (a * m[u][cc].w + na * r.w) * sc;
            nt_store_f4(op + (cidx + cc * 16) * 4, w);
        }
    }
}

extern "C" void kernel_launch(void* const* d_in, const int* in_sizes, int n_in,
                              void* d_out, int out_size, void* d_ws, size_t ws_size,
                              hipStream_t stream) {
    const float* reprs      = (const float*)d_in[0];
    const float* memory     = (const float*)d_in[1];
    const float* alpha      = (const float*)d_in[2];
    const int*   track_idxs = (const int*)d_in[3];   // harness converts int64 -> int32
    float*       out        = (float*)d_out;

    int*   cnt   = (int*)d_ws;                                  // 16 KB
    int*   list  = (int*)((char*)d_ws + T_TRK * sizeof(int));   // 1 MB (MAXD=64)
    float* norm2 = (float*)((char*)d_ws + T_TRK * sizeof(int)
                            + (size_t)T_TRK * MAXD * sizeof(int)); // 32 KB

    (void)hipMemsetAsync(cnt, 0, T_TRK * sizeof(int), stream);
    prep<<<B_DET / 4, 256, 0, stream>>>(reprs, track_idxs, cnt, list, norm2);
    fused_update<<<T_TRK, 256, 0, stream>>>(reprs, memory, alpha, cnt, list, norm2, out);
}

// Round 14
// 94.428 us; speedup vs baseline: 1.0299x; 1.0299x over previous
//
#include <hip/hip_runtime.h>
#include <stdint.h>

#define B_DET 8192
#define N_DIM 256
#define T_TRK 4096
#define Q_SLOT 64
#define MAXD   64          // list capacity; P(D>64) ~ 0 for Binomial(8192, 1/4096)
#define EPSF   1e-9f

typedef unsigned long long ull;
typedef float nfloat4 __attribute__((ext_vector_type(4)));   // native vec for nt builtins

// Monotone map fp32 -> uint32 (ascending), and its exact inverse.
__device__ __forceinline__ uint32_t f32_key(float f) {
    uint32_t u = __float_as_uint(f);
    return (u & 0x80000000u) ? ~u : (u | 0x80000000u);
}
__device__ __forceinline__ float key_inv(uint32_t k) {
    uint32_t u = (k & 0x80000000u) ? (k ^ 0x80000000u) : ~k;
    return __uint_as_float(u);
}

__device__ __forceinline__ void nt_store_f4(float* p, float4 v) {
    nfloat4 nv; nv.x = v.x; nv.y = v.y; nv.z = v.z; nv.w = v.w;
    __builtin_nontemporal_store(nv, reinterpret_cast<nfloat4*>(p));
}

// Prep (merged): 2048 blocks x 256. Each block: 4 detection-row norms (one
// per wave, full-wave butterfly) + buckets 4 detections (threads 0..3).
// cnt[] must be zeroed beforehand. List order is nondeterministic (atomics)
// but argmin compares by VALUE (key, b, d) -> selection order-independent.
__global__ __launch_bounds__(256)
void prep(const float* __restrict__ reprs, const int* __restrict__ track_idxs,
          int* __restrict__ cnt, int* __restrict__ list,
          float* __restrict__ norm2) {
    const int wave = threadIdx.x >> 6;
    const int lane = threadIdx.x & 63;
    const int row  = blockIdx.x * 4 + wave;

    const float4 v = reinterpret_cast<const float4*>(reprs + (size_t)row * N_DIM)[lane];
    float ss = v.x * v.x + v.y * v.y + v.z * v.z + v.w * v.w;
    #pragma unroll
    for (int o = 32; o >= 1; o >>= 1) ss += __shfl_xor(ss, o, 64);
    if (lane == 0) norm2[row] = ss;

    if (threadIdx.x < 4) {
        const int b = blockIdx.x * 4 + threadIdx.x;
        const int t = track_idxs[b];
        const int slot = atomicAdd(&cnt[t], 1);
        if (slot < MAXD) list[t * MAXD + slot] = b;
    }
}

// Pass 2: fully independent waves — no LDS, no barriers. Block = (track,
// half) after XCD-contiguous swizzle; wave = quarter of the half (8 rows).
// Grouped layout: lane l (group g=l>>4, col c=l&15) holds float4-columns
// c, c+16, c+32, c+48 of memory row qbase + i*4 + g.
// KEY ORDERING: the 8 grouped m-row loads issue FIRST, unconditionally —
// before cnt/list are consumed — so the block-uniform scalar loads and the
// D==0 branch resolve under the m-load shadow (both paths use the same
// registers; D==0 just stores them back, same bytes, permuted lanes).
// Dot reduce: 4-stage butterfly (xor 8,4,2,1) within the 16-lane group,
// 4 slots at once, detection rows pipelined one ahead from global (L2-hot).
// Argmin via packed (f32key(dot), b, d) u64 min == exact first-occurrence
// tie-break. Norm closed-form (memory rows unit-norm):
//   ||a*m+(1-a)r||^2 = a^2 + (1-a)^2||r||^2 + 2a(1-a)dot,
// dot decoded bit-exactly from winning key, ||r||^2 looked up.
// All out-stores NONTEMPORAL (measured -14% in R10).
__global__ __launch_bounds__(256)
void fused_update(const float* __restrict__ reprs,
                  const float* __restrict__ memory,
                  const float* __restrict__ alpha,
                  const int* __restrict__ cnt,
                  const int* __restrict__ list,
                  const float* __restrict__ norm2,
                  float* __restrict__ out) {
    const int bid  = blockIdx.x;
    const int swz  = (bid & 7) * (8192 >> 3) + (bid >> 3);   // 8192 % 8 == 0
    const int t    = swz >> 1;
    const int wave = threadIdx.x >> 6;
    const int lane = threadIdx.x & 63;
    const int g    = lane >> 4;
    const int cidx = lane & 15;
    const int qbase = (swz & 1) * 32 + wave * 8;
    const size_t tbase = (size_t)t * Q_SLOT * N_DIM;

    // (1) long-latency work first: grouped preload of this wave's 8 rows
    float4 m[2][4];
    #pragma unroll
    for (int i = 0; i < 2; ++i) {
        const float* rp = memory + tbase + (size_t)(qbase + i * 4 + g) * N_DIM;
        #pragma unroll
        for (int c = 0; c < 4; ++c)
            m[i][c] = reinterpret_cast<const float4*>(rp)[cidx + c * 16];
    }

    // (2) block-uniform scalars resolve under the load shadow
    int D = cnt[t];
    if (D > MAXD) D = MAXD;

    if (D == 0) {
        // untouched: store the grouped registers straight back
        #pragma unroll
        for (int i = 0; i < 2; ++i) {
            float* op = out + tbase + (size_t)(qbase + i * 4 + g) * N_DIM;
            #pragma unroll
            for (int c = 0; c < 4; ++c)
                nt_store_f4(op + (cidx + c * 16) * 4, m[i][c]);
        }
        return;
    }

    ull best[2] = { ~0ULL, ~0ULL };

    // software-pipelined detection loop (load d+1 while reducing d)
    int b_cur = list[t * MAXD];
    float4 rc[4];
    {
        const float* rp = reprs + (size_t)b_cur * N_DIM;
        #pragma unroll
        for (int cc = 0; cc < 4; ++cc)
            rc[cc] = reinterpret_cast<const float4*>(rp)[cidx + cc * 16];
    }

    for (int d = 0; d < D; ++d) {
        int b_nxt = 0;
        float4 rn[4];
        if (d + 1 < D) {
            b_nxt = list[t * MAXD + d + 1];
            const float* rp = reprs + (size_t)b_nxt * N_DIM;
            #pragma unroll
            for (int cc = 0; cc < 4; ++cc)
                rn[cc] = reinterpret_cast<const float4*>(rp)[cidx + cc * 16];
        }

        float p0 = 0.0f, p1 = 0.0f;
        #pragma unroll
        for (int cc = 0; cc < 4; ++cc) {
            p0 += m[0][cc].x * rc[cc].x + m[0][cc].y * rc[cc].y
                + m[0][cc].z * rc[cc].z + m[0][cc].w * rc[cc].w;
            p1 += m[1][cc].x * rc[cc].x + m[1][cc].y * rc[cc].y
                + m[1][cc].z * rc[cc].z + m[1][cc].w * rc[cc].w;
        }
        // 4-stage butterfly within each 16-lane group
        #pragma unroll
        for (int o = 8; o >= 1; o >>= 1) {
            p0 += __shfl_xor(p0, o, 64);
            p1 += __shfl_xor(p1, o, 64);
        }

        const uint32_t bd = ((uint32_t)b_cur << 6) | (uint32_t)d;
        const ull k0 = ((ull)f32_key(p0) << 32) | bd;
        const ull k1 = ((ull)f32_key(p1) << 32) | bd;
        if (k0 < best[0]) best[0] = k0;
        if (k1 < best[1]) best[1] = k1;

        b_cur = b_nxt;
        #pragma unroll
        for (int cc = 0; cc < 4; ++cc) rc[cc] = rn[cc];
    }

    #pragma unroll
    for (int i = 0; i < 2; ++i) {
        const int q = qbase + i * 4 + g;
        const int   bsel = (int)(((uint32_t)best[i]) >> 6);
        const float dot  = key_inv((uint32_t)(best[i] >> 32));
        const float a    = alpha[q];
        const float na   = 1.0f - a;

        const float* rp = reprs + (size_t)bsel * N_DIM;   // L1/L2-hot refetch
        const float nrm2 = a * a + na * na * norm2[bsel] + 2.0f * a * na * dot;
        const float sc = 1.0f / (sqrtf(nrm2) + EPSF);

        float* op = out + tbase + (size_t)q * N_DIM;
        #pragma unroll
        for (int cc = 0; cc < 4; ++cc) {
            const float4 r = reinterpret_cast<const float4*>(rp)[cidx + cc * 16];
            float4 u;
            u.x = (a * m[i][cc].x + na * r.x) * sc;
            u.y = (a * m[i][cc].y + na * r.y) * sc;
            u.z = (a * m[i][cc].z + na * r.z) * sc;
            u.w = (a * m[i][cc].w + na * r.w) * sc;
            nt_store_f4(op + (cidx + cc * 16) * 4, u);
        }
    }
}

extern "C" void kernel_launch(void* const* d_in, const int* in_sizes, int n_in,
                              void* d_out, int out_size, void* d_ws, size_t ws_size,
                              hipStream_t stream) {
    const float* reprs      = (const float*)d_in[0];
    const float* memory     = (const float*)d_in[1];
    const float* alpha      = (const float*)d_in[2];
    const int*   track_idxs = (const int*)d_in[3];   // harness converts int64 -> int32
    float*       out        = (float*)d_out;

    int*   cnt   = (int*)d_ws;                                  // 16 KB
    int*   list  = (int*)((char*)d_ws + T_TRK * sizeof(int));   // 1 MB (MAXD=64)
    float* norm2 = (float*)((char*)d_ws + T_TRK * sizeof(int)
                            + (size_t)T_TRK * MAXD * sizeof(int)); // 32 KB

    (void)hipMemsetAsync(cnt, 0, T_TRK * sizeof(int), stream);
    prep<<<B_DET / 4, 256, 0, stream>>>(reprs, track_idxs, cnt, list, norm2);
    fused_update<<<T_TRK * 2, 256, 0, stream>>>(reprs, memory, alpha, cnt, list, norm2, out);
}